// Round 9
// baseline (479.717 us; speedup 1.0000x reference)
//
#include <hip/hip_runtime.h>
#include <hip/hip_fp16.h>

#define N_NODES 100000
#define N_EDGES 1600000
#define C 128

// binned CSR build (fixed-capacity buckets)
#define NB_SHIFT 10
#define NB (1 << NB_SHIFT)                        // 1024 nodes per bucket
#define NBKT ((N_NODES + NB - 1) >> NB_SHIFT)     // 98 buckets
#define CAP 20480                                 // edges per bucket window (avg 16327)
#define CPT 4096                                  // edges per stage block
#define STG_BLOCKS ((N_EDGES + CPT - 1) / CPT)    // 391
#define CVB 782                                   // cvt blocks (512 thr * 8 float4)
#define PWB 32                                    // prepw blocks

// sliced mean
#define NPAIR 4                                   // node-pairs per wave
#define NODES_PER_BLK (4 * 2 * NPAIR)             // 32
#define MEAN_G ((N_NODES + NODES_PER_BLK - 1) / NODES_PER_BLK)  // 3125

typedef _Float16 half8 __attribute__((ext_vector_type(8)));
typedef float f32x4 __attribute__((ext_vector_type(4)));

// ---------------- fused pre-pass: cvt | prepw | binned stage ----------------

__global__ __launch_bounds__(512) void k_fusedA(
    const float* __restrict__ x, const int* __restrict__ src,
    const int* __restrict__ dst, const float* __restrict__ Wl1,
    const float* __restrict__ Wr1, const float* __restrict__ Wl2,
    const float* __restrict__ Wr2, int* __restrict__ gcur,
    uint2* __restrict__ S, __half* __restrict__ Xh, __half* __restrict__ Wc1,
    __half* __restrict__ Wc2) {
    __shared__ int hist[128], sc[128], lstart[128], gbaseL[128];
    __shared__ uint2 stg[CPT];
    const int bid = blockIdx.x;
    const int t = threadIdx.x;

    if (bid < CVB) {
        const float4* xin = (const float4*)x;
        __half2* yout = (__half2*)Xh;
#pragma unroll
        for (int i = 0; i < 8; i++) {
            int idx = bid * 4096 + i * 512 + t;
            if (idx < N_NODES * C / 4) {
                float4 v = xin[idx];
                yout[idx * 2] = __floats2half2_rn(v.x, v.y);
                yout[idx * 2 + 1] = __floats2half2_rn(v.z, v.w);
            }
        }
        return;
    }
    if (bid < CVB + PWB) {
        int i0 = ((bid - CVB) * 512 + t) * 4;
#pragma unroll
        for (int m = 0; m < 4; m++) {
            int i = i0 + m;
            if (i < 2 * 128 * 256) {
                int set = i >> 15;
                int j = i & 32767;
                int n_ = j >> 8, k = j & 255;
                const float* Wl = set ? Wl2 : Wl1;
                const float* Wr = set ? Wr2 : Wr1;
                float v = (k < 128) ? Wl[n_ * 128 + k] : Wr[n_ * 128 + (k - 128)];
                (set ? Wc2 : Wc1)[j] = __float2half_rn(v);
            }
        }
        return;
    }

    // ---- binned stage ----
    int base = (bid - CVB - PWB) * CPT;
    int cnt = N_EDGES - base;
    if (cnt > CPT) cnt = CPT;
    if (t < 128) hist[t] = 0;
    __syncthreads();
    unsigned s_[8], d_[8];
    int r_[8], b_[8];
#pragma unroll
    for (int i = 0; i < 8; i++) {
        int li = i * 512 + t;
        if (li < cnt) {
            int e = base + li;
            s_[i] = src[e];
            d_[i] = dst[e];
            b_[i] = d_[i] >> NB_SHIFT;
            r_[i] = atomicAdd(&hist[b_[i]], 1);
        } else {
            r_[i] = -1;
        }
    }
    __syncthreads();
    int hv = (t < 128) ? hist[t] : 0;
    if (t < 128) sc[t] = hv;
    __syncthreads();
    for (int off = 1; off < 128; off <<= 1) {
        int u = (t < 128 && t >= off) ? sc[t - off] : 0;
        __syncthreads();
        if (t < 128) sc[t] += u;
        __syncthreads();
    }
    if (t < 128) lstart[t] = sc[t] - hv;
    if (t < NBKT && hv) gbaseL[t] = t * CAP + atomicAdd(&gcur[t], hv);
    __syncthreads();
#pragma unroll
    for (int i = 0; i < 8; i++)
        if (r_[i] >= 0) stg[lstart[b_[i]] + r_[i]] = make_uint2(s_[i], d_[i]);
    __syncthreads();
    for (int slot = t; slot < cnt; slot += 512) {
        uint2 ed = stg[slot];
        int b = ed.y >> NB_SHIFT;
        S[gbaseL[b] + (slot - lstart[b])] = ed;
    }
}

// ---- per-bucket fine counting sort -> rowbeg/rowend + col (gapped windows) ----
__global__ __launch_bounds__(1024) void k_bfine(const uint2* __restrict__ S,
                                                const int* __restrict__ gcur,
                                                int* __restrict__ rowbeg,
                                                int* __restrict__ rowend,
                                                int* __restrict__ col) {
    __shared__ int hist[NB];
    __shared__ int wsum[16];
    int t = threadIdx.x, b = blockIdx.x;
    int nbeg = b << NB_SHIFT;
    int ebeg = b * CAP;
    int cnt = gcur[b];
    hist[t] = 0;
    __syncthreads();
    for (int e = t; e < cnt; e += 1024) atomicAdd(&hist[S[ebeg + e].y - nbeg], 1);
    __syncthreads();
    int v = hist[t];
    int inc = v;
    int lane = t & 63, wid = t >> 6;
#pragma unroll
    for (int off = 1; off < 64; off <<= 1) {
        int u = __shfl_up(inc, off);
        if (lane >= off) inc += u;
    }
    if (lane == 63) wsum[wid] = inc;
    __syncthreads();
    if (t < 16) {
        int wi = wsum[t];
#pragma unroll
        for (int off = 1; off < 16; off <<= 1) {
            int u = __shfl_up(wi, off);
            if (t >= off) wi += u;
        }
        wsum[t] = wi;
    }
    __syncthreads();
    int woff = (wid == 0) ? 0 : wsum[wid - 1];
    int excl = inc - v + woff;
    int g = nbeg + t;
    if (g < N_NODES) {
        rowbeg[g] = ebeg + excl;
        rowend[g] = ebeg + excl + v;
    }
    __syncthreads();
    hist[t] = excl;
    __syncthreads();
    for (int e = t; e < cnt; e += 1024) {
        uint2 ed = S[ebeg + e];
        int p = atomicAdd(&hist[ed.y - nbeg], 1);
        col[ebeg + p] = ed.x;
    }
}

// ------------- mean aggregation: channel-sliced for per-XCD L2 residency -------
// blockIdx.x & 7 = channel slice (16 ch = 32B of each row); with round-robin
// block->XCD dispatch every slice lands on one XCD: working set 100K x 32B =
// 3.2MB < 4MB L2. Per wave: 2 nodes (lane>>5), 16 edge slots x 2 segs; cross-
// slot reduce via shfl_xor(2|4|8|16) which preserves seg(bit0)/half(bit5).

__global__ __launch_bounds__(256) void k_mean_sl(const __half* __restrict__ X,
                                                 __half* __restrict__ M,
                                                 const int* __restrict__ rowbeg,
                                                 const int* __restrict__ rowend,
                                                 const int* __restrict__ col) {
    int slice = blockIdx.x & 7;
    int g = blockIdx.x >> 3;
    int wave = threadIdx.x >> 6, lane = threadIdx.x & 63;
    int half_ = lane >> 5;
    int es = (lane >> 1) & 15;  // edge slot
    int seg = lane & 1;         // 16B half of this slice's 32B
    const __half* Xs = X + slice * 16 + seg * 8;
    int base = (g * 4 + wave) * (2 * NPAIR);
#pragma unroll
    for (int i = 0; i < NPAIR; i++) {
        int node = base + i * 2 + half_;
        if (node >= N_NODES) continue;
        int beg = rowbeg[node], end = rowend[node];
        float acc[8];
#pragma unroll
        for (int j = 0; j < 8; j++) acc[j] = 0.f;
        for (int e0 = beg; e0 < end; e0 += 16) {
            int ee = e0 + es;
            bool val = (ee < end);
            int s = col[val ? ee : (end - 1)];
            uint4 v = *(const uint4*)(Xs + (size_t)s * C);
            if (val) {
                const __half2* h = (const __half2*)&v;
#pragma unroll
                for (int q = 0; q < 4; q++) {
                    float2 f = __half22float2(h[q]);
                    acc[2 * q] += f.x;
                    acc[2 * q + 1] += f.y;
                }
            }
        }
#pragma unroll
        for (int j = 0; j < 8; j++) {
            acc[j] += __shfl_xor(acc[j], 2);
            acc[j] += __shfl_xor(acc[j], 4);
            acc[j] += __shfl_xor(acc[j], 8);
            acc[j] += __shfl_xor(acc[j], 16);
        }
        int deg = end - beg;
        float inv = 1.0f / (float)((deg > 0) ? deg : 1);
        if (es == 0) {
            __half2 o[4];
#pragma unroll
            for (int q = 0; q < 4; q++)
                o[q] = __floats2half2_rn(acc[2 * q] * inv, acc[2 * q + 1] * inv);
            *(uint4*)(M + (size_t)node * C + slice * 16 + seg * 8) = *(uint4*)o;
        }
    }
}

// ---------------- MFMA GEMM: relu(A0@W[:, :128]^T + A1@W[:, 128:]^T + b) --------

template <int HEAD>
__global__ __launch_bounds__(256) void k_gemm_f16(
    const __half* __restrict__ A0, const __half* __restrict__ A1,
    const __half* __restrict__ W, const float* __restrict__ bias,
    __half* __restrict__ Hout, const float* __restrict__ Wo,
    const float* __restrict__ bo, float* __restrict__ out) {
    __shared__ __half As[2][128][40];
    __shared__ __half Bs[2][128][40];
    __shared__ float outs[2][128];

    const int tid = threadIdx.x;
    const int n0 = blockIdx.x * 128;
    const int wid = tid >> 6, lane = tid & 63;
    const int wr = wid >> 1, wc = wid & 1;
    const int l15 = lane & 15, lk = lane >> 4;

    f32x4 acc[4][4];
#pragma unroll
    for (int m = 0; m < 4; m++)
#pragma unroll
        for (int n = 0; n < 4; n++) acc[m][n] = (f32x4)(0.0f);

    const int row0 = tid >> 2, seg0 = (tid & 3) * 8;
    const int row1 = (tid + 256) >> 2, seg1 = seg0;

    uint4 ra[2], rb[2];
    auto stage_load = [&](int t) {
        int kg = t * 32;
        const __half* Ap = (kg < 128) ? A0 : A1;
        int k0 = kg & 127;
        int n_ = n0 + row0;
        ra[0] = (n_ < N_NODES) ? *(const uint4*)(Ap + (size_t)n_ * C + k0 + seg0)
                               : make_uint4(0, 0, 0, 0);
        rb[0] = *(const uint4*)(W + row0 * 256 + kg + seg0);
        n_ = n0 + row1;
        ra[1] = (n_ < N_NODES) ? *(const uint4*)(Ap + (size_t)n_ * C + k0 + seg1)
                               : make_uint4(0, 0, 0, 0);
        rb[1] = *(const uint4*)(W + row1 * 256 + kg + seg1);
    };
    auto stage_write = [&](int b) {
        *(uint4*)&As[b][row0][seg0] = ra[0];
        *(uint4*)&Bs[b][row0][seg0] = rb[0];
        *(uint4*)&As[b][row1][seg1] = ra[1];
        *(uint4*)&Bs[b][row1][seg1] = rb[1];
    };

    stage_load(0);
    stage_write(0);
    __syncthreads();

    for (int t = 0; t < 8; t++) {
        int cur = t & 1;
        if (t < 7) stage_load(t + 1);
        half8 af[4], bf[4];
#pragma unroll
        for (int m = 0; m < 4; m++)
            af[m] = *(const half8*)&As[cur][wr * 64 + m * 16 + l15][lk * 8];
#pragma unroll
        for (int n = 0; n < 4; n++)
            bf[n] = *(const half8*)&Bs[cur][wc * 64 + n * 16 + l15][lk * 8];
#pragma unroll
        for (int m = 0; m < 4; m++)
#pragma unroll
            for (int n = 0; n < 4; n++)
                acc[m][n] =
                    __builtin_amdgcn_mfma_f32_16x16x32_f16(af[m], bf[n], acc[m][n], 0, 0, 0);
        if (t < 7) stage_write(cur ^ 1);
        __syncthreads();
    }

    float bv[4];
#pragma unroll
    for (int n = 0; n < 4; n++) bv[n] = bias[wc * 64 + n * 16 + l15];
#pragma unroll
    for (int m = 0; m < 4; m++)
#pragma unroll
        for (int n = 0; n < 4; n++)
#pragma unroll
            for (int r = 0; r < 4; r++)
                acc[m][n][r] = fmaxf(acc[m][n][r] + bv[n], 0.f);

    if (!HEAD) {
#pragma unroll
        for (int m = 0; m < 4; m++) {
#pragma unroll
            for (int r = 0; r < 4; r++) {
                int n_ = n0 + wr * 64 + m * 16 + lk * 4 + r;
                if (n_ < N_NODES) {
#pragma unroll
                    for (int n = 0; n < 4; n++)
                        Hout[(size_t)n_ * C + wc * 64 + n * 16 + l15] =
                            __float2half_rn(acc[m][n][r]);
                }
            }
        }
    } else {
        float wv[4];
#pragma unroll
        for (int n = 0; n < 4; n++) wv[n] = Wo[wc * 64 + n * 16 + l15];
#pragma unroll
        for (int m = 0; m < 4; m++) {
#pragma unroll
            for (int r = 0; r < 4; r++) {
                float p = acc[m][0][r] * wv[0] + acc[m][1][r] * wv[1] +
                          acc[m][2][r] * wv[2] + acc[m][3][r] * wv[3];
                p += __shfl_xor(p, 1);
                p += __shfl_xor(p, 2);
                p += __shfl_xor(p, 4);
                p += __shfl_xor(p, 8);
                if (l15 == 0) outs[wc][wr * 64 + m * 16 + lk * 4 + r] = p;
            }
        }
        __syncthreads();
        if (tid < 128) {
            int n_ = n0 + tid;
            if (n_ < N_NODES) out[n_] = outs[0][tid] + outs[1][tid] + bo[0];
        }
    }
}

// ---------------- launch ----------------

extern "C" void kernel_launch(void* const* d_in, const int* in_sizes, int n_in,
                              void* d_out, int out_size, void* d_ws, size_t ws_size,
                              hipStream_t stream) {
    const float* x   = (const float*)d_in[0];
    const int*   ei  = (const int*)d_in[1];
    const float* Wl1 = (const float*)d_in[2];
    const float* bl1 = (const float*)d_in[3];
    const float* Wr1 = (const float*)d_in[4];
    const float* Wl2 = (const float*)d_in[5];
    const float* bl2 = (const float*)d_in[6];
    const float* Wr2 = (const float*)d_in[7];
    const float* Wo  = (const float*)d_in[8];
    const float* bo  = (const float*)d_in[9];
    float* out = (float*)d_out;

    const int* src = ei;
    const int* dst = ei + N_EDGES;

    char* ws = (char*)d_ws;
    auto carve = [&](size_t bytes) {
        char* p = ws;
        ws += (bytes + 1023) & ~(size_t)1023;
        return p;
    };
    int*    gcur   = (int*)carve((size_t)NBKT * 4);
    int*    rowbeg = (int*)carve((size_t)N_NODES * 4);
    int*    rowend = (int*)carve((size_t)N_NODES * 4);
    int*    col    = (int*)carve((size_t)NBKT * CAP * 4);
    uint2*  S      = (uint2*)carve((size_t)NBKT * CAP * 8);
    __half* Xh     = (__half*)carve((size_t)N_NODES * C * 2);
    __half* Mh     = (__half*)carve((size_t)N_NODES * C * 2);
    __half* Hh     = (__half*)carve((size_t)N_NODES * C * 2);
    __half* Wc1    = (__half*)carve((size_t)128 * 256 * 2);
    __half* Wc2    = (__half*)carve((size_t)128 * 256 * 2);

    hipMemsetAsync(gcur, 0, (size_t)NBKT * 4, stream);

    // fused cvt + weight-pack + binned stage
    k_fusedA<<<CVB + PWB + STG_BLOCKS, 512, 0, stream>>>(
        x, src, dst, Wl1, Wr1, Wl2, Wr2, gcur, S, Xh, Wc1, Wc2);
    // per-bucket counting sort -> rowbeg/rowend + col
    k_bfine<<<NBKT, 1024, 0, stream>>>(S, gcur, rowbeg, rowend, col);

    dim3 gM(MEAN_G * 8), b256(256);
    dim3 gG((N_NODES + 127) / 128);

    // layer 1
    k_mean_sl<<<gM, b256, 0, stream>>>(Xh, Mh, rowbeg, rowend, col);
    k_gemm_f16<0><<<gG, b256, 0, stream>>>(Xh, Mh, Wc1, bl1, Hh, nullptr, nullptr, nullptr);
    // layer 2 + fused head
    k_mean_sl<<<gM, b256, 0, stream>>>(Hh, Mh, rowbeg, rowend, col);
    k_gemm_f16<1><<<gG, b256, 0, stream>>>(Hh, Mh, Wc2, bl2, nullptr, Wo, bo, out);
}

// Round 10
// 215.374 us; speedup vs baseline: 2.2274x; 2.2274x over previous
//
#include <hip/hip_runtime.h>
#include <hip/hip_fp16.h>

#define N_NODES 100000
#define N_EDGES 1600000
#define C 128

// binned CSR build (fixed-capacity buckets)
#define NB_SHIFT 10
#define NB (1 << NB_SHIFT)                        // 1024 nodes per bucket
#define NBKT ((N_NODES + NB - 1) >> NB_SHIFT)     // 98 buckets
#define CAP 20480                                 // edges per bucket window (avg 16327)
#define CPT 4096                                  // edges per stage block
#define STG_BLOCKS ((N_EDGES + CPT - 1) / CPT)    // 391
#define CVB 782                                   // cvt blocks (512 thr * 8 float4)
#define PWB 32                                    // prepw blocks

typedef _Float16 half8 __attribute__((ext_vector_type(8)));
typedef float f32x4 __attribute__((ext_vector_type(4)));

// ---------------- fused pre-pass: cvt | prepw | binned stage ----------------

__global__ __launch_bounds__(512) void k_fusedA(
    const float* __restrict__ x, const int* __restrict__ src,
    const int* __restrict__ dst, const float* __restrict__ Wl1,
    const float* __restrict__ Wr1, const float* __restrict__ Wl2,
    const float* __restrict__ Wr2, int* __restrict__ gcur,
    uint2* __restrict__ S, __half* __restrict__ Xh, __half* __restrict__ Wc1,
    __half* __restrict__ Wc2) {
    __shared__ int hist[128], sc[128], lstart[128], gbaseL[128];
    __shared__ uint2 stg[CPT];
    const int bid = blockIdx.x;
    const int t = threadIdx.x;

    if (bid < CVB) {
        const float4* xin = (const float4*)x;
        __half2* yout = (__half2*)Xh;
#pragma unroll
        for (int i = 0; i < 8; i++) {
            int idx = bid * 4096 + i * 512 + t;
            if (idx < N_NODES * C / 4) {
                float4 v = xin[idx];
                yout[idx * 2] = __floats2half2_rn(v.x, v.y);
                yout[idx * 2 + 1] = __floats2half2_rn(v.z, v.w);
            }
        }
        return;
    }
    if (bid < CVB + PWB) {
        int i0 = ((bid - CVB) * 512 + t) * 4;
#pragma unroll
        for (int m = 0; m < 4; m++) {
            int i = i0 + m;
            if (i < 2 * 128 * 256) {
                int set = i >> 15;
                int j = i & 32767;
                int n_ = j >> 8, k = j & 255;
                const float* Wl = set ? Wl2 : Wl1;
                const float* Wr = set ? Wr2 : Wr1;
                float v = (k < 128) ? Wl[n_ * 128 + k] : Wr[n_ * 128 + (k - 128)];
                (set ? Wc2 : Wc1)[j] = __float2half_rn(v);
            }
        }
        return;
    }

    // ---- binned stage ----
    int base = (bid - CVB - PWB) * CPT;
    int cnt = N_EDGES - base;
    if (cnt > CPT) cnt = CPT;
    if (t < 128) hist[t] = 0;
    __syncthreads();
    unsigned s_[8], d_[8];
    int r_[8], b_[8];
#pragma unroll
    for (int i = 0; i < 8; i++) {
        int li = i * 512 + t;
        if (li < cnt) {
            int e = base + li;
            s_[i] = src[e];
            d_[i] = dst[e];
            b_[i] = d_[i] >> NB_SHIFT;
            r_[i] = atomicAdd(&hist[b_[i]], 1);
        } else {
            r_[i] = -1;
        }
    }
    __syncthreads();
    int hv = (t < 128) ? hist[t] : 0;
    if (t < 128) sc[t] = hv;
    __syncthreads();
    for (int off = 1; off < 128; off <<= 1) {
        int u = (t < 128 && t >= off) ? sc[t - off] : 0;
        __syncthreads();
        if (t < 128) sc[t] += u;
        __syncthreads();
    }
    if (t < 128) lstart[t] = sc[t] - hv;
    if (t < NBKT && hv) gbaseL[t] = t * CAP + atomicAdd(&gcur[t], hv);
    __syncthreads();
#pragma unroll
    for (int i = 0; i < 8; i++)
        if (r_[i] >= 0) stg[lstart[b_[i]] + r_[i]] = make_uint2(s_[i], d_[i]);
    __syncthreads();
    for (int slot = t; slot < cnt; slot += 512) {
        uint2 ed = stg[slot];
        int b = ed.y >> NB_SHIFT;
        S[gbaseL[b] + (slot - lstart[b])] = ed;
    }
}

// ---- per-bucket fine counting sort -> rowbeg/rowend + col (gapped windows) ----
__global__ __launch_bounds__(1024) void k_bfine(const uint2* __restrict__ S,
                                                const int* __restrict__ gcur,
                                                int* __restrict__ rowbeg,
                                                int* __restrict__ rowend,
                                                int* __restrict__ col) {
    __shared__ int hist[NB];
    __shared__ int wsum[16];
    int t = threadIdx.x, b = blockIdx.x;
    int nbeg = b << NB_SHIFT;
    int ebeg = b * CAP;
    int cnt = gcur[b];
    hist[t] = 0;
    __syncthreads();
    for (int e = t; e < cnt; e += 1024) atomicAdd(&hist[S[ebeg + e].y - nbeg], 1);
    __syncthreads();
    int v = hist[t];
    int inc = v;
    int lane = t & 63, wid = t >> 6;
#pragma unroll
    for (int off = 1; off < 64; off <<= 1) {
        int u = __shfl_up(inc, off);
        if (lane >= off) inc += u;
    }
    if (lane == 63) wsum[wid] = inc;
    __syncthreads();
    if (t < 16) {
        int wi = wsum[t];
#pragma unroll
        for (int off = 1; off < 16; off <<= 1) {
            int u = __shfl_up(wi, off);
            if (t >= off) wi += u;
        }
        wsum[t] = wi;
    }
    __syncthreads();
    int woff = (wid == 0) ? 0 : wsum[wid - 1];
    int excl = inc - v + woff;
    int g = nbeg + t;
    if (g < N_NODES) {
        rowbeg[g] = ebeg + excl;
        rowend[g] = ebeg + excl + v;
    }
    __syncthreads();
    hist[t] = excl;
    __syncthreads();
    for (int e = t; e < cnt; e += 1024) {
        uint2 ed = S[ebeg + e];
        int p = atomicAdd(&hist[ed.y - nbeg], 1);
        col[ebeg + p] = ed.x;
    }
}

// ---------------- mean aggregation: one 16-lane group per node (R6 best) ---------

__global__ __launch_bounds__(256) void k_mean_f16(const __half* __restrict__ X,
                                                  __half* __restrict__ M,
                                                  const int* __restrict__ rowbeg,
                                                  const int* __restrict__ rowend,
                                                  const int* __restrict__ col) {
    int node = blockIdx.x * 16 + (threadIdx.x >> 4);
    if (node >= N_NODES) return;
    int seg = threadIdx.x & 15;  // 16B segment within 256B row
    int beg = rowbeg[node], end = rowend[node];
    float acc[8];
#pragma unroll
    for (int i = 0; i < 8; i++) acc[i] = 0.f;
    for (int e = beg; e < end; e += 8) {
        uint4 v[8];
        bool val[8];
#pragma unroll
        for (int u = 0; u < 8; u++) {
            int ee = e + u;
            val[u] = (ee < end);
            int s = col[val[u] ? ee : (end - 1)];
            v[u] = *(const uint4*)(X + (size_t)s * C + seg * 8);
        }
#pragma unroll
        for (int u = 0; u < 8; u++) {
            if (val[u]) {
                const __half2* h = (const __half2*)&v[u];
#pragma unroll
                for (int p = 0; p < 4; p++) {
                    float2 f = __half22float2(h[p]);
                    acc[2 * p] += f.x;
                    acc[2 * p + 1] += f.y;
                }
            }
        }
    }
    int deg = end - beg;
    float inv = 1.0f / (float)((deg > 0) ? deg : 1);
    __half2 o[4];
#pragma unroll
    for (int p = 0; p < 4; p++)
        o[p] = __floats2half2_rn(acc[2 * p] * inv, acc[2 * p + 1] * inv);
    *(uint4*)(M + (size_t)node * C + seg * 8) = *(uint4*)o;
}

// ---------------- GEMM v2: 64-row x 128-col tile, single-shot K=256 stage -------
// 1563 blocks (2x TLP vs 782), 256 threads = 4 waves, wave tile 64x32.
// A-tile (64 rows x K=256, self||mean concat) staged once in LDS (32KB + pad);
// ONE barrier, then pure MFMA burst; B read direct from L2-hot 64KB packed W.
// HEAD=1 fuses the output head.

template <int HEAD>
__global__ __launch_bounds__(256) void k_gemm2(
    const __half* __restrict__ A0, const __half* __restrict__ A1,
    const __half* __restrict__ W, const float* __restrict__ bias,
    __half* __restrict__ Hout, const float* __restrict__ Wo,
    const float* __restrict__ bo, float* __restrict__ out) {
    __shared__ __half As[64][264];  // pad 8 halves: frag reads 2-way conflict (free)
    __shared__ float outs[4][64];
    const int tid = threadIdx.x;
    const int r0 = blockIdx.x * 64;

    // ---- stage A: 2048 16B-slots; slot s -> row s>>5, seg s&31 (0-15: A0, 16-31: A1)
#pragma unroll
    for (int i = 0; i < 8; i++) {
        int s = tid + i * 256;
        int row = s >> 5, sg = s & 31;
        int gr = r0 + row;
        gr = (gr < N_NODES) ? gr : (N_NODES - 1);
        uint4 v;
        if (sg < 16)
            v = *(const uint4*)(A0 + (size_t)gr * C + sg * 8);
        else
            v = *(const uint4*)(A1 + (size_t)gr * C + (sg - 16) * 8);
        *(uint4*)&As[row][sg * 8] = v;
    }
    __syncthreads();

    const int wid = tid >> 6, lane = tid & 63;
    const int l15 = lane & 15, lk = lane >> 4;

    f32x4 acc[4][2];
#pragma unroll
    for (int m = 0; m < 4; m++)
#pragma unroll
        for (int n = 0; n < 2; n++) acc[m][n] = (f32x4)(0.0f);

#pragma unroll
    for (int c = 0; c < 8; c++) {
        half8 af[4], bf[2];
#pragma unroll
        for (int m = 0; m < 4; m++)
            af[m] = *(const half8*)&As[m * 16 + l15][c * 32 + lk * 8];
#pragma unroll
        for (int n = 0; n < 2; n++)
            bf[n] = *(const half8*)(W + (size_t)(wid * 32 + n * 16 + l15) * 256 +
                                    c * 32 + lk * 8);
#pragma unroll
        for (int m = 0; m < 4; m++)
#pragma unroll
            for (int n = 0; n < 2; n++)
                acc[m][n] =
                    __builtin_amdgcn_mfma_f32_16x16x32_f16(af[m], bf[n], acc[m][n], 0, 0, 0);
    }

    // ---- epilogue: bias + relu ----
    float bv[2];
#pragma unroll
    for (int n = 0; n < 2; n++) bv[n] = bias[wid * 32 + n * 16 + l15];
#pragma unroll
    for (int m = 0; m < 4; m++)
#pragma unroll
        for (int n = 0; n < 2; n++)
#pragma unroll
            for (int r = 0; r < 4; r++)
                acc[m][n][r] = fmaxf(acc[m][n][r] + bv[n], 0.f);

    if (!HEAD) {
        // C/D layout: out-col = wid*32 + n*16 + l15, row_local = m*16 + lk*4 + r
#pragma unroll
        for (int m = 0; m < 4; m++) {
#pragma unroll
            for (int r = 0; r < 4; r++) {
                int row = r0 + m * 16 + lk * 4 + r;
                if (row < N_NODES) {
#pragma unroll
                    for (int n = 0; n < 2; n++)
                        Hout[(size_t)row * C + wid * 32 + n * 16 + l15] =
                            __float2half_rn(acc[m][n][r]);
                }
            }
        }
    } else {
        float wv[2];
#pragma unroll
        for (int n = 0; n < 2; n++) wv[n] = Wo[wid * 32 + n * 16 + l15];
#pragma unroll
        for (int m = 0; m < 4; m++) {
#pragma unroll
            for (int r = 0; r < 4; r++) {
                float p = acc[m][0][r] * wv[0] + acc[m][1][r] * wv[1];
                p += __shfl_xor(p, 1);
                p += __shfl_xor(p, 2);
                p += __shfl_xor(p, 4);
                p += __shfl_xor(p, 8);
                if (l15 == 0) outs[wid][m * 16 + lk * 4 + r] = p;
            }
        }
        __syncthreads();
        if (tid < 64) {
            int row = r0 + tid;
            if (row < N_NODES)
                out[row] = outs[0][tid] + outs[1][tid] + outs[2][tid] + outs[3][tid] +
                           bo[0];
        }
    }
}

// ---------------- launch ----------------

extern "C" void kernel_launch(void* const* d_in, const int* in_sizes, int n_in,
                              void* d_out, int out_size, void* d_ws, size_t ws_size,
                              hipStream_t stream) {
    const float* x   = (const float*)d_in[0];
    const int*   ei  = (const int*)d_in[1];
    const float* Wl1 = (const float*)d_in[2];
    const float* bl1 = (const float*)d_in[3];
    const float* Wr1 = (const float*)d_in[4];
    const float* Wl2 = (const float*)d_in[5];
    const float* bl2 = (const float*)d_in[6];
    const float* Wr2 = (const float*)d_in[7];
    const float* Wo  = (const float*)d_in[8];
    const float* bo  = (const float*)d_in[9];
    float* out = (float*)d_out;

    const int* src = ei;
    const int* dst = ei + N_EDGES;

    char* ws = (char*)d_ws;
    auto carve = [&](size_t bytes) {
        char* p = ws;
        ws += (bytes + 1023) & ~(size_t)1023;
        return p;
    };
    int*    gcur   = (int*)carve((size_t)NBKT * 4);
    int*    rowbeg = (int*)carve((size_t)N_NODES * 4);
    int*    rowend = (int*)carve((size_t)N_NODES * 4);
    int*    col    = (int*)carve((size_t)NBKT * CAP * 4);
    uint2*  S      = (uint2*)carve((size_t)NBKT * CAP * 8);
    __half* Xh     = (__half*)carve((size_t)N_NODES * C * 2);
    __half* Mh     = (__half*)carve((size_t)N_NODES * C * 2);
    __half* Hh     = (__half*)carve((size_t)N_NODES * C * 2);
    __half* Wc1    = (__half*)carve((size_t)128 * 256 * 2);
    __half* Wc2    = (__half*)carve((size_t)128 * 256 * 2);

    hipMemsetAsync(gcur, 0, (size_t)NBKT * 4, stream);

    // fused cvt + weight-pack + binned stage
    k_fusedA<<<CVB + PWB + STG_BLOCKS, 512, 0, stream>>>(
        x, src, dst, Wl1, Wr1, Wl2, Wr2, gcur, S, Xh, Wc1, Wc2);
    // per-bucket counting sort -> rowbeg/rowend + col
    k_bfine<<<NBKT, 1024, 0, stream>>>(S, gcur, rowbeg, rowend, col);

    dim3 gN((N_NODES + 15) / 16), b256(256);
    dim3 gG((N_NODES + 63) / 64);

    // layer 1
    k_mean_f16<<<gN, b256, 0, stream>>>(Xh, Mh, rowbeg, rowend, col);
    k_gemm2<0><<<gG, b256, 0, stream>>>(Xh, Mh, Wc1, bl1, Hh, nullptr, nullptr, nullptr);
    // layer 2 + fused head
    k_mean_f16<<<gN, b256, 0, stream>>>(Hh, Mh, rowbeg, rowend, col);
    k_gemm2<1><<<gG, b256, 0, stream>>>(Hh, Mh, Wc2, bl2, nullptr, Wo, bo, out);
}

// Round 11
// 172.243 us; speedup vs baseline: 2.7851x; 1.2504x over previous
//
#include <hip/hip_runtime.h>
#include <hip/hip_fp16.h>
#include <hip/hip_fp8.h>

#define N_NODES 100000
#define N_EDGES 1600000
#define C 128

// binned CSR build (fixed-capacity buckets)
#define NB_SHIFT 10
#define NB (1 << NB_SHIFT)                        // 1024 nodes per bucket
#define NBKT ((N_NODES + NB - 1) >> NB_SHIFT)     // 98 buckets
#define CAP 20480                                 // edges per bucket window (avg 16327)
#define CPT 4096                                  // edges per stage block
#define STG_BLOCKS ((N_EDGES + CPT - 1) / CPT)    // 391
#define CVB 782                                   // cvt blocks (512 thr * 8 float4)
#define PWB 32                                    // prepw blocks

typedef _Float16 half8 __attribute__((ext_vector_type(8)));
typedef float f32x4 __attribute__((ext_vector_type(4)));
typedef float f32x2 __attribute__((ext_vector_type(2)));

// ---- fp8 e4m3 helpers (HW cvt on gfx950; OCP format) ----
__device__ inline void fp8x4_to_f32(unsigned w, float* f) {
#if __has_builtin(__builtin_amdgcn_cvt_pk_f32_fp8)
    f32x2 lo = __builtin_amdgcn_cvt_pk_f32_fp8((int)w, false);
    f32x2 hi = __builtin_amdgcn_cvt_pk_f32_fp8((int)w, true);
    f[0] = lo[0]; f[1] = lo[1]; f[2] = hi[0]; f[3] = hi[1];
#else
    for (int i = 0; i < 4; i++) {
        __hip_fp8_e4m3 v;
        v.__x = (unsigned char)(w >> (8 * i));
        f[i] = (float)v;
    }
#endif
}

__device__ inline unsigned f32x4_to_fp8(float a, float b, float c, float d) {
#if __has_builtin(__builtin_amdgcn_cvt_pk_fp8_f32)
    int t = __builtin_amdgcn_cvt_pk_fp8_f32(a, b, 0, false);
    t = __builtin_amdgcn_cvt_pk_fp8_f32(c, d, t, true);
    return (unsigned)t;
#else
    __hip_fp8_e4m3 fa(a), fb(b), fc(c), fd(d);
    return (unsigned)fa.__x | ((unsigned)fb.__x << 8) | ((unsigned)fc.__x << 16) |
           ((unsigned)fd.__x << 24);
#endif
}

__device__ inline unsigned f32x2_to_fp8(float a, float b) {
#if __has_builtin(__builtin_amdgcn_cvt_pk_fp8_f32)
    return (unsigned)__builtin_amdgcn_cvt_pk_fp8_f32(a, b, 0, false);
#else
    __hip_fp8_e4m3 fa(a), fb(b);
    return (unsigned)fa.__x | ((unsigned)fb.__x << 8);
#endif
}

// ---------------- fused pre-pass: cvt | prepw | binned stage ----------------

__global__ __launch_bounds__(512) void k_fusedA(
    const float* __restrict__ x, const int* __restrict__ src,
    const int* __restrict__ dst, const float* __restrict__ Wl1,
    const float* __restrict__ Wr1, const float* __restrict__ Wl2,
    const float* __restrict__ Wr2, int* __restrict__ gcur,
    uint2* __restrict__ S, __half* __restrict__ Xh, unsigned* __restrict__ X8u,
    __half* __restrict__ Wc1, __half* __restrict__ Wc2) {
    __shared__ int hist[128], sc[128], lstart[128], gbaseL[128];
    __shared__ uint2 stg[CPT];
    const int bid = blockIdx.x;
    const int t = threadIdx.x;

    if (bid < CVB) {
        const float4* xin = (const float4*)x;
        __half2* yout = (__half2*)Xh;
#pragma unroll
        for (int i = 0; i < 8; i++) {
            int idx = bid * 4096 + i * 512 + t;
            if (idx < N_NODES * C / 4) {
                float4 v = xin[idx];
                yout[idx * 2] = __floats2half2_rn(v.x, v.y);
                yout[idx * 2 + 1] = __floats2half2_rn(v.z, v.w);
                X8u[idx] = f32x4_to_fp8(v.x, v.y, v.z, v.w);
            }
        }
        return;
    }
    if (bid < CVB + PWB) {
        int i0 = ((bid - CVB) * 512 + t) * 4;
#pragma unroll
        for (int m = 0; m < 4; m++) {
            int i = i0 + m;
            if (i < 2 * 128 * 256) {
                int set = i >> 15;
                int j = i & 32767;
                int n_ = j >> 8, k = j & 255;
                const float* Wl = set ? Wl2 : Wl1;
                const float* Wr = set ? Wr2 : Wr1;
                float v = (k < 128) ? Wl[n_ * 128 + k] : Wr[n_ * 128 + (k - 128)];
                (set ? Wc2 : Wc1)[j] = __float2half_rn(v);
            }
        }
        return;
    }

    // ---- binned stage ----
    int base = (bid - CVB - PWB) * CPT;
    int cnt = N_EDGES - base;
    if (cnt > CPT) cnt = CPT;
    if (t < 128) hist[t] = 0;
    __syncthreads();
    unsigned s_[8], d_[8];
    int r_[8], b_[8];
#pragma unroll
    for (int i = 0; i < 8; i++) {
        int li = i * 512 + t;
        if (li < cnt) {
            int e = base + li;
            s_[i] = src[e];
            d_[i] = dst[e];
            b_[i] = d_[i] >> NB_SHIFT;
            r_[i] = atomicAdd(&hist[b_[i]], 1);
        } else {
            r_[i] = -1;
        }
    }
    __syncthreads();
    int hv = (t < 128) ? hist[t] : 0;
    if (t < 128) sc[t] = hv;
    __syncthreads();
    for (int off = 1; off < 128; off <<= 1) {
        int u = (t < 128 && t >= off) ? sc[t - off] : 0;
        __syncthreads();
        if (t < 128) sc[t] += u;
        __syncthreads();
    }
    if (t < 128) lstart[t] = sc[t] - hv;
    if (t < NBKT && hv) gbaseL[t] = t * CAP + atomicAdd(&gcur[t], hv);
    __syncthreads();
#pragma unroll
    for (int i = 0; i < 8; i++)
        if (r_[i] >= 0) stg[lstart[b_[i]] + r_[i]] = make_uint2(s_[i], d_[i]);
    __syncthreads();
    for (int slot = t; slot < cnt; slot += 512) {
        uint2 ed = stg[slot];
        int b = ed.y >> NB_SHIFT;
        S[gbaseL[b] + (slot - lstart[b])] = ed;
    }
}

// ---- per-bucket fine counting sort -> rowbeg/rowend + col (gapped windows) ----
__global__ __launch_bounds__(1024) void k_bfine(const uint2* __restrict__ S,
                                                const int* __restrict__ gcur,
                                                int* __restrict__ rowbeg,
                                                int* __restrict__ rowend,
                                                int* __restrict__ col) {
    __shared__ int hist[NB];
    __shared__ int wsum[16];
    int t = threadIdx.x, b = blockIdx.x;
    int nbeg = b << NB_SHIFT;
    int ebeg = b * CAP;
    int cnt = gcur[b];
    hist[t] = 0;
    __syncthreads();
    for (int e = t; e < cnt; e += 1024) atomicAdd(&hist[S[ebeg + e].y - nbeg], 1);
    __syncthreads();
    int v = hist[t];
    int inc = v;
    int lane = t & 63, wid = t >> 6;
#pragma unroll
    for (int off = 1; off < 64; off <<= 1) {
        int u = __shfl_up(inc, off);
        if (lane >= off) inc += u;
    }
    if (lane == 63) wsum[wid] = inc;
    __syncthreads();
    if (t < 16) {
        int wi = wsum[t];
#pragma unroll
        for (int off = 1; off < 16; off <<= 1) {
            int u = __shfl_up(wi, off);
            if (t >= off) wi += u;
        }
        wsum[t] = wi;
    }
    __syncthreads();
    int woff = (wid == 0) ? 0 : wsum[wid - 1];
    int excl = inc - v + woff;
    int g = nbeg + t;
    if (g < N_NODES) {
        rowbeg[g] = ebeg + excl;
        rowend[g] = ebeg + excl + v;
    }
    __syncthreads();
    hist[t] = excl;
    __syncthreads();
    for (int e = t; e < cnt; e += 1024) {
        uint2 ed = S[ebeg + e];
        int p = atomicAdd(&hist[ed.y - nbeg], 1);
        col[ebeg + p] = ed.x;
    }
}

// ---------------- mean aggregation over fp8 rows: 8 lanes per node --------------
// Row = 128B fp8 = 8 lanes x uint4 (16 channels/lane). 32 nodes/block ->
// ~256 chains/CU. 8-deep unrolled edge chunks (8 x 16B outstanding/lane).
// HW v_cvt_pk_f32_fp8 unpack; fp32 accumulate; fp16 mean output (GEMM operand).

__global__ __launch_bounds__(256) void k_mean_fp8(const unsigned char* __restrict__ X8,
                                                  __half* __restrict__ M,
                                                  const int* __restrict__ rowbeg,
                                                  const int* __restrict__ rowend,
                                                  const int* __restrict__ col) {
    int node = blockIdx.x * 32 + (threadIdx.x >> 3);
    if (node >= N_NODES) return;
    int seg = threadIdx.x & 7;  // 16B = 16 fp8 channels
    int beg = rowbeg[node], end = rowend[node];
    float acc[16];
#pragma unroll
    for (int i = 0; i < 16; i++) acc[i] = 0.f;
    for (int e = beg; e < end; e += 8) {
        uint4 v[8];
        bool val[8];
#pragma unroll
        for (int u = 0; u < 8; u++) {
            int ee = e + u;
            val[u] = (ee < end);
            int s = col[val[u] ? ee : (end - 1)];
            v[u] = *(const uint4*)(X8 + (size_t)s * C + seg * 16);
        }
#pragma unroll
        for (int u = 0; u < 8; u++) {
            if (val[u]) {
                const unsigned* w = (const unsigned*)&v[u];
#pragma unroll
                for (int q = 0; q < 4; q++) {
                    float f[4];
                    fp8x4_to_f32(w[q], f);
                    acc[4 * q + 0] += f[0];
                    acc[4 * q + 1] += f[1];
                    acc[4 * q + 2] += f[2];
                    acc[4 * q + 3] += f[3];
                }
            }
        }
    }
    int deg = end - beg;
    float inv = 1.0f / (float)((deg > 0) ? deg : 1);
    __half2 o[8];
#pragma unroll
    for (int q = 0; q < 8; q++)
        o[q] = __floats2half2_rn(acc[2 * q] * inv, acc[2 * q + 1] * inv);
    uint4* dst0 = (uint4*)(M + (size_t)node * C + seg * 16);
    dst0[0] = ((uint4*)o)[0];
    dst0[1] = ((uint4*)o)[1];
}

// ---------------- GEMM v2: 64-row x 128-col tile, single-shot K=256 stage -------
// HEAD=0 additionally writes fp8 copy of H (gather operand for layer 2).

template <int HEAD>
__global__ __launch_bounds__(256) void k_gemm2(
    const __half* __restrict__ A0, const __half* __restrict__ A1,
    const __half* __restrict__ W, const float* __restrict__ bias,
    __half* __restrict__ Hout, unsigned char* __restrict__ H8,
    const float* __restrict__ Wo, const float* __restrict__ bo,
    float* __restrict__ out) {
    __shared__ __half As[64][264];  // pad 8 halves: frag reads 2-way conflict (free)
    __shared__ float outs[4][64];
    const int tid = threadIdx.x;
    const int r0 = blockIdx.x * 64;

    // ---- stage A: 2048 16B-slots; slot s -> row s>>5, seg s&31 (0-15: A0, 16-31: A1)
#pragma unroll
    for (int i = 0; i < 8; i++) {
        int s = tid + i * 256;
        int row = s >> 5, sg = s & 31;
        int gr = r0 + row;
        gr = (gr < N_NODES) ? gr : (N_NODES - 1);
        uint4 v;
        if (sg < 16)
            v = *(const uint4*)(A0 + (size_t)gr * C + sg * 8);
        else
            v = *(const uint4*)(A1 + (size_t)gr * C + (sg - 16) * 8);
        *(uint4*)&As[row][sg * 8] = v;
    }
    __syncthreads();

    const int wid = tid >> 6, lane = tid & 63;
    const int l15 = lane & 15, lk = lane >> 4;

    f32x4 acc[4][2];
#pragma unroll
    for (int m = 0; m < 4; m++)
#pragma unroll
        for (int n = 0; n < 2; n++) acc[m][n] = (f32x4)(0.0f);

#pragma unroll
    for (int c = 0; c < 8; c++) {
        half8 af[4], bf[2];
#pragma unroll
        for (int m = 0; m < 4; m++)
            af[m] = *(const half8*)&As[m * 16 + l15][c * 32 + lk * 8];
#pragma unroll
        for (int n = 0; n < 2; n++)
            bf[n] = *(const half8*)(W + (size_t)(wid * 32 + n * 16 + l15) * 256 +
                                    c * 32 + lk * 8);
#pragma unroll
        for (int m = 0; m < 4; m++)
#pragma unroll
            for (int n = 0; n < 2; n++)
                acc[m][n] =
                    __builtin_amdgcn_mfma_f32_16x16x32_f16(af[m], bf[n], acc[m][n], 0, 0, 0);
    }

    // ---- epilogue: bias + relu ----
    float bv[2];
#pragma unroll
    for (int n = 0; n < 2; n++) bv[n] = bias[wid * 32 + n * 16 + l15];
#pragma unroll
    for (int m = 0; m < 4; m++)
#pragma unroll
        for (int n = 0; n < 2; n++)
#pragma unroll
            for (int r = 0; r < 4; r++)
                acc[m][n][r] = fmaxf(acc[m][n][r] + bv[n], 0.f);

    if (!HEAD) {
        // C/D layout: out-col = wid*32 + n*16 + l15, row_local = m*16 + lk*4 + r
#pragma unroll
        for (int m = 0; m < 4; m++) {
#pragma unroll
            for (int r = 0; r < 4; r++) {
                int row = r0 + m * 16 + lk * 4 + r;
                if (row < N_NODES) {
#pragma unroll
                    for (int n = 0; n < 2; n++)
                        Hout[(size_t)row * C + wid * 32 + n * 16 + l15] =
                            __float2half_rn(acc[m][n][r]);
                    unsigned t8 = f32x2_to_fp8(acc[m][0][r], acc[m][1][r]);
                    H8[(size_t)row * C + wid * 32 + l15] = (unsigned char)(t8 & 0xff);
                    H8[(size_t)row * C + wid * 32 + 16 + l15] =
                        (unsigned char)((t8 >> 8) & 0xff);
                }
            }
        }
    } else {
        float wv[2];
#pragma unroll
        for (int n = 0; n < 2; n++) wv[n] = Wo[wid * 32 + n * 16 + l15];
#pragma unroll
        for (int m = 0; m < 4; m++) {
#pragma unroll
            for (int r = 0; r < 4; r++) {
                float p = acc[m][0][r] * wv[0] + acc[m][1][r] * wv[1];
                p += __shfl_xor(p, 1);
                p += __shfl_xor(p, 2);
                p += __shfl_xor(p, 4);
                p += __shfl_xor(p, 8);
                if (l15 == 0) outs[wid][m * 16 + lk * 4 + r] = p;
            }
        }
        __syncthreads();
        if (tid < 64) {
            int row = r0 + tid;
            if (row < N_NODES)
                out[row] = outs[0][tid] + outs[1][tid] + outs[2][tid] + outs[3][tid] +
                           bo[0];
        }
    }
}

// ---------------- launch ----------------

extern "C" void kernel_launch(void* const* d_in, const int* in_sizes, int n_in,
                              void* d_out, int out_size, void* d_ws, size_t ws_size,
                              hipStream_t stream) {
    const float* x   = (const float*)d_in[0];
    const int*   ei  = (const int*)d_in[1];
    const float* Wl1 = (const float*)d_in[2];
    const float* bl1 = (const float*)d_in[3];
    const float* Wr1 = (const float*)d_in[4];
    const float* Wl2 = (const float*)d_in[5];
    const float* bl2 = (const float*)d_in[6];
    const float* Wr2 = (const float*)d_in[7];
    const float* Wo  = (const float*)d_in[8];
    const float* bo  = (const float*)d_in[9];
    float* out = (float*)d_out;

    const int* src = ei;
    const int* dst = ei + N_EDGES;

    char* ws = (char*)d_ws;
    auto carve = [&](size_t bytes) {
        char* p = ws;
        ws += (bytes + 1023) & ~(size_t)1023;
        return p;
    };
    int*      gcur   = (int*)carve((size_t)NBKT * 4);
    int*      rowbeg = (int*)carve((size_t)N_NODES * 4);
    int*      rowend = (int*)carve((size_t)N_NODES * 4);
    int*      col    = (int*)carve((size_t)NBKT * CAP * 4);
    uint2*    S      = (uint2*)carve((size_t)NBKT * CAP * 8);
    __half*   Xh     = (__half*)carve((size_t)N_NODES * C * 2);
    __half*   Mh     = (__half*)carve((size_t)N_NODES * C * 2);
    __half*   Hh     = (__half*)carve((size_t)N_NODES * C * 2);
    unsigned char* X8 = (unsigned char*)carve((size_t)N_NODES * C);
    unsigned char* H8 = (unsigned char*)carve((size_t)N_NODES * C);
    __half*   Wc1    = (__half*)carve((size_t)128 * 256 * 2);
    __half*   Wc2    = (__half*)carve((size_t)128 * 256 * 2);

    hipMemsetAsync(gcur, 0, (size_t)NBKT * 4, stream);

    // fused cvt(+fp8) + weight-pack + binned stage
    k_fusedA<<<CVB + PWB + STG_BLOCKS, 512, 0, stream>>>(
        x, src, dst, Wl1, Wr1, Wl2, Wr2, gcur, S, Xh, (unsigned*)X8, Wc1, Wc2);
    // per-bucket counting sort -> rowbeg/rowend + col
    k_bfine<<<NBKT, 1024, 0, stream>>>(S, gcur, rowbeg, rowend, col);

    dim3 gM((N_NODES + 31) / 32), b256(256);
    dim3 gG((N_NODES + 63) / 64);

    // layer 1
    k_mean_fp8<<<gM, b256, 0, stream>>>(X8, Mh, rowbeg, rowend, col);
    k_gemm2<0><<<gG, b256, 0, stream>>>(Xh, Mh, Wc1, bl1, Hh, H8, nullptr, nullptr,
                                        nullptr);
    // layer 2 + fused head
    k_mean_fp8<<<gM, b256, 0, stream>>>(H8, Mh, rowbeg, rowend, col);
    k_gemm2<1><<<gG, b256, 0, stream>>>(Hh, Mh, Wc2, bl2, nullptr, nullptr, Wo, bo,
                                        out);
}